// Round 1
// baseline (414.488 us; speedup 1.0000x reference)
//
#include <hip/hip_runtime.h>
#include <float.h>

#define NB 32
#define D  2048
#define NC 1023

// ws layout (float offsets)
#define OFF_LN   0                      // ln_feat [NB*D]
#define OFF_SW   (NB*D)                 // float2 sw[NB][NC]
#define OFF_MM   (OFF_SW + 2*NB*NC)     // smax[NB], smin[NB]
#define OFF_OUT1 (OFF_MM + 2*NB)        // out1 [NB*D]
#define OFF_LN2  (OFF_OUT1 + NB*D)      // ln2  [NB*D]
#define OFF_H    (OFF_LN2 + NB*D)       // h    [NB*D]

__device__ __forceinline__ float wred_sum(float x){
  #pragma unroll
  for (int o = 32; o; o >>= 1) x += __shfl_xor(x, o);
  return x;
}

// ---------------------------------------------------------------------------
// Kernel 1: per-batch prep. LN1, gather, kq/vw fold, s/w vectors, smax/smin.
// ---------------------------------------------------------------------------
__global__ __launch_bounds__(256) void prep_kernel(
    const float* __restrict__ feat, const int* __restrict__ idx,
    const float* __restrict__ ln_w, const float* __restrict__ ln_b,
    const float* __restrict__ q_w,  const float* __restrict__ k_w,
    const float* __restrict__ v_w,  const float* __restrict__ conv_w,
    float* __restrict__ ws)
{
  __shared__ float sh_feat[D];
  __shared__ float sh_shuf[D];
  __shared__ float red_s[4][2];
  __shared__ float red_k[4][8];
  __shared__ float red_mm[4][2];

  const int b = blockIdx.x;
  const int t = threadIdx.x;
  const int wid = t >> 6;

  // ---- load features row into LDS + sum/sumsq
  const float4* fb4 = (const float4*)(feat + b * D);
  float4* sf4 = (float4*)sh_feat;
  float4 fv[2];
  float s1 = 0.f, s2 = 0.f;
  #pragma unroll
  for (int j = 0; j < 2; ++j) {
    float4 v = fb4[t + j * 256];
    fv[j] = v;
    sf4[t + j * 256] = v;
    s1 += (v.x + v.y) + (v.z + v.w);
    s2 += fmaf(v.x, v.x, fmaf(v.y, v.y, fmaf(v.z, v.z, v.w * v.w)));
  }

  // ---- kq[j] = sum_k q_w[k]*k_w[k,j];  vw[j] = sum_v conv_w[v]*v_w[v,j]
  float pk[4] = {0,0,0,0}, pv[4] = {0,0,0,0};
  if (t < 128) {
    float qv = q_w[t], cv = conv_w[t];
    #pragma unroll
    for (int j = 0; j < 4; ++j) {
      pk[j] = qv * k_w[t * 4 + j];
      pv[j] = cv * v_w[t * 4 + j];
    }
  }
  s1 = wred_sum(s1); s2 = wred_sum(s2);
  #pragma unroll
  for (int j = 0; j < 4; ++j) { pk[j] = wred_sum(pk[j]); pv[j] = wred_sum(pv[j]); }
  if ((t & 63) == 0) {
    red_s[wid][0] = s1; red_s[wid][1] = s2;
    #pragma unroll
    for (int j = 0; j < 4; ++j) { red_k[wid][j] = pk[j]; red_k[wid][4 + j] = pv[j]; }
  }
  __syncthreads();

  const float S1 = red_s[0][0] + red_s[1][0] + red_s[2][0] + red_s[3][0];
  const float S2 = red_s[0][1] + red_s[1][1] + red_s[2][1] + red_s[3][1];
  float kq[4], vw[4];
  #pragma unroll
  for (int j = 0; j < 4; ++j) {
    kq[j] = red_k[0][j] + red_k[1][j] + red_k[2][j] + red_k[3][j];
    vw[j] = red_k[0][4+j] + red_k[1][4+j] + red_k[2][4+j] + red_k[3][4+j];
  }
  const float mean = S1 * (1.f / D);
  const float rstd = rsqrtf(S2 * (1.f / D) - mean * mean + 1e-5f);

  // ---- write ln_feat (alpha values)
  float* lnp = ws + OFF_LN + b * D;
  const float4* lw4 = (const float4*)ln_w;
  const float4* lb4 = (const float4*)ln_b;
  #pragma unroll
  for (int j = 0; j < 2; ++j) {
    int i = t + j * 256;
    float4 v = fv[j], w = lw4[i], bb = lb4[i], o;
    o.x = (v.x - mean) * rstd * w.x + bb.x;
    o.y = (v.y - mean) * rstd * w.y + bb.y;
    o.z = (v.z - mean) * rstd * w.z + bb.z;
    o.w = (v.w - mean) * rstd * w.w + bb.w;
    ((float4*)lnp)[i] = o;
  }

  // ---- gather shuffled row (sh_feat complete after first sync)
  #pragma unroll
  for (int j = 0; j < 8; ++j) {
    int i = t + j * 256;
    sh_shuf[i] = sh_feat[idx[i]];
  }
  __syncthreads();

  // ---- s[c], w[c] + min/max of s
  float2* swp = (float2*)(ws + OFF_SW) + b * NC;
  float lmax = -FLT_MAX, lmin = FLT_MAX;
  #pragma unroll
  for (int j = 0; j < 4; ++j) {
    int c = t + j * 256;
    if (c < NC) {
      float a0 = sh_shuf[2*c], a1 = sh_shuf[2*c+1], a2 = sh_shuf[2*c+2], a3 = sh_shuf[2*c+3];
      float sv = fmaf(a0, kq[0], fmaf(a1, kq[1], fmaf(a2, kq[2], a3 * kq[3])));
      float wv = fmaf(a0, vw[0], fmaf(a1, vw[1], fmaf(a2, vw[2], a3 * vw[3])));
      float2 p; p.x = sv; p.y = wv;
      swp[c] = p;
      lmax = fmaxf(lmax, sv);
      lmin = fminf(lmin, sv);
    }
  }
  #pragma unroll
  for (int o = 32; o; o >>= 1) {
    lmax = fmaxf(lmax, __shfl_xor(lmax, o));
    lmin = fminf(lmin, __shfl_xor(lmin, o));
  }
  if ((t & 63) == 0) { red_mm[wid][0] = lmax; red_mm[wid][1] = lmin; }
  __syncthreads();
  if (t == 0) {
    ws[OFF_MM + b]      = fmaxf(fmaxf(red_mm[0][0], red_mm[1][0]), fmaxf(red_mm[2][0], red_mm[3][0]));
    ws[OFF_MM + NB + b] = fminf(fminf(red_mm[0][1], red_mm[1][1]), fminf(red_mm[2][1], red_mm[3][1]));
  }
}

// ---------------------------------------------------------------------------
// Kernel 2: one block per (b,q) row. Single exp pass, write attn + out1.
// ---------------------------------------------------------------------------
__global__ __launch_bounds__(128) void attn_kernel(
    const float* __restrict__ feat, float* __restrict__ ws,
    float* __restrict__ out)
{
  __shared__ float ebuf[1024];
  __shared__ float sred[4];

  const int row = blockIdx.x;          // b*2048 + q
  const int b = row >> 11;
  const int t = threadIdx.x;

  const float alpha = ws[OFF_LN + row];
  const float smax = ws[OFF_MM + b], smin = ws[OFF_MM + NB + b];
  const float m = (alpha >= 0.f) ? alpha * smax : alpha * smin;
  const float2* sw = (const float2*)(ws + OFF_SW) + b * NC;

  float l = 0.f, acc = 0.f;
  #pragma unroll
  for (int j = 0; j < 8; ++j) {
    int c = t + j * 128;
    if (c < NC) {
      float2 p = sw[c];
      float e = __expf(fmaf(alpha, p.x, -m));
      ebuf[c] = e;
      l += e;
      acc = fmaf(e, p.y, acc);
    }
  }
  #pragma unroll
  for (int o = 32; o; o >>= 1) { l += __shfl_xor(l, o); acc += __shfl_xor(acc, o); }
  const int wid = t >> 6;
  if ((t & 63) == 0) { sred[wid * 2] = l; sred[wid * 2 + 1] = acc; }
  __syncthreads();
  l = sred[0] + sred[2];
  acc = sred[1] + sred[3];
  const float inv = 1.f / l;

  float* ap = out + NB * D + (size_t)row * NC;
  #pragma unroll
  for (int j = 0; j < 8; ++j) {
    int c = t + j * 128;
    if (c < NC) ap[c] = ebuf[c] * inv;
  }
  if (t == 0) ws[OFF_OUT1 + row] = fmaf(acc, inv, feat[row]);
}

// ---------------------------------------------------------------------------
// Kernel 3: LN2 over out1; init h = w1_b, init out = out1 + w2_b.
// ---------------------------------------------------------------------------
__global__ __launch_bounds__(256) void ln2_init_kernel(
    const float* __restrict__ bnw, const float* __restrict__ bnb,
    const float* __restrict__ w1b, const float* __restrict__ w2b,
    float* __restrict__ ws, float* __restrict__ out)
{
  __shared__ float red_s[4][2];
  const int b = blockIdx.x, t = threadIdx.x;
  const int wid = t >> 6;
  const float4* x4 = (const float4*)(ws + OFF_OUT1 + b * D);
  float4 xv[2];
  float s1 = 0.f, s2 = 0.f;
  #pragma unroll
  for (int j = 0; j < 2; ++j) {
    float4 v = x4[t + j * 256];
    xv[j] = v;
    s1 += (v.x + v.y) + (v.z + v.w);
    s2 += fmaf(v.x, v.x, fmaf(v.y, v.y, fmaf(v.z, v.z, v.w * v.w)));
  }
  s1 = wred_sum(s1); s2 = wred_sum(s2);
  if ((t & 63) == 0) { red_s[wid][0] = s1; red_s[wid][1] = s2; }
  __syncthreads();
  const float S1 = red_s[0][0] + red_s[1][0] + red_s[2][0] + red_s[3][0];
  const float S2 = red_s[0][1] + red_s[1][1] + red_s[2][1] + red_s[3][1];
  const float mean = S1 * (1.f / D);
  const float rstd = rsqrtf(S2 * (1.f / D) - mean * mean + 1e-6f);

  float4* ln2p = (float4*)(ws + OFF_LN2 + b * D);
  float4* hp   = (float4*)(ws + OFF_H   + b * D);
  float4* op   = (float4*)out + b * (D / 4);
  const float4* bw4 = (const float4*)bnw;
  const float4* bb4 = (const float4*)bnb;
  const float4* w1b4 = (const float4*)w1b;
  const float4* w2b4 = (const float4*)w2b;
  #pragma unroll
  for (int j = 0; j < 2; ++j) {
    int i = t + j * 256;
    float4 v = xv[j], w = bw4[i], bb = bb4[i], o;
    o.x = (v.x - mean) * rstd * w.x + bb.x;
    o.y = (v.y - mean) * rstd * w.y + bb.y;
    o.z = (v.z - mean) * rstd * w.z + bb.z;
    o.w = (v.w - mean) * rstd * w.w + bb.w;
    ln2p[i] = o;
    hp[i] = w1b4[i];
    float4 w2 = w2b4[i], oo;
    oo.x = v.x + w2.x; oo.y = v.y + w2.y; oo.z = v.z + w2.z; oo.w = v.w + w2.w;
    op[i] = oo;
  }
}

// ---------------------------------------------------------------------------
// Kernels 4/5: out[m,n] += sum_k X[m,k]*W[n,k]   (M=32, N=K=2048)
// grid = 64 n-chunks x 4 k-splits; block 256. RELU applied to X on load.
// ---------------------------------------------------------------------------
template<int RELU>
__global__ __launch_bounds__(256) void gemm_kernel(
    const float* __restrict__ X, const float* __restrict__ W,
    float* __restrict__ out)
{
  __shared__ float xs[32 * 68];
  __shared__ float wt[32 * 68];
  const int nb = blockIdx.x & 63;
  const int kb = blockIdx.x >> 6;
  const int n0 = nb * 32;
  const int t = threadIdx.x;
  const int row = t >> 3, kl = t & 7;     // compute coords
  const int tr = t >> 4, tc = (t & 15) * 4; // staging coords

  float acc[32];
  #pragma unroll
  for (int m = 0; m < 32; ++m) acc[m] = 0.f;

  for (int ch = 0; ch < 8; ++ch) {
    const int kc = kb * 512 + ch * 64;
    #pragma unroll
    for (int jj = 0; jj < 2; ++jj) {
      int r = tr + jj * 16;
      float4 v = *(const float4*)(X + r * 2048 + kc + tc);
      if (RELU) {
        v.x = fmaxf(v.x, 0.f); v.y = fmaxf(v.y, 0.f);
        v.z = fmaxf(v.z, 0.f); v.w = fmaxf(v.w, 0.f);
      }
      *(float4*)(xs + r * 68 + tc) = v;
      float4 wv = *(const float4*)(W + (n0 + r) * 2048 + kc + tc);
      *(float4*)(wt + r * 68 + tc) = wv;
    }
    __syncthreads();
    const float4 wa = *(float4*)(wt + row * 68 + kl * 8);
    const float4 wb = *(float4*)(wt + row * 68 + kl * 8 + 4);
    #pragma unroll
    for (int m = 0; m < 32; ++m) {
      float4 xa = *(float4*)(xs + m * 68 + kl * 8);
      float4 xb = *(float4*)(xs + m * 68 + kl * 8 + 4);
      acc[m] = fmaf(xa.x, wa.x, fmaf(xa.y, wa.y, fmaf(xa.z, wa.z, fmaf(xa.w, wa.w,
               fmaf(xb.x, wb.x, fmaf(xb.y, wb.y, fmaf(xb.z, wb.z, fmaf(xb.w, wb.w, acc[m]))))))));
    }
    __syncthreads();
  }
  #pragma unroll
  for (int m = 0; m < 32; ++m) {
    acc[m] += __shfl_xor(acc[m], 1);
    acc[m] += __shfl_xor(acc[m], 2);
    acc[m] += __shfl_xor(acc[m], 4);
  }
  #pragma unroll
  for (int i = 0; i < 4; ++i) {
    int m = kl * 4 + i;
    atomicAdd(out + m * 2048 + n0 + row, acc[m]);
  }
}

// ---------------------------------------------------------------------------
extern "C" void kernel_launch(void* const* d_in, const int* in_sizes, int n_in,
                              void* d_out, int out_size, void* d_ws, size_t ws_size,
                              hipStream_t stream)
{
  (void)in_sizes; (void)n_in; (void)out_size; (void)ws_size;
  const float* feat   = (const float*)d_in[0];
  const int*   idx    = (const int*)d_in[1];
  const float* ln_w   = (const float*)d_in[2];
  const float* ln_b   = (const float*)d_in[3];
  const float* q_w    = (const float*)d_in[4];
  const float* k_w    = (const float*)d_in[5];
  const float* v_w    = (const float*)d_in[6];
  const float* conv_w = (const float*)d_in[7];
  const float* bnw    = (const float*)d_in[8];
  const float* bnb    = (const float*)d_in[9];
  const float* w1w    = (const float*)d_in[10];
  const float* w1b    = (const float*)d_in[11];
  const float* w2w    = (const float*)d_in[12];
  const float* w2b    = (const float*)d_in[13];
  float* out = (float*)d_out;
  float* ws  = (float*)d_ws;

  prep_kernel<<<dim3(NB), dim3(256), 0, stream>>>(feat, idx, ln_w, ln_b, q_w, k_w, v_w, conv_w, ws);
  attn_kernel<<<dim3(NB * D), dim3(128), 0, stream>>>(feat, ws, out);
  ln2_init_kernel<<<dim3(NB), dim3(256), 0, stream>>>(bnw, bnb, w1b, w2b, ws, out);
  gemm_kernel<0><<<dim3(256), dim3(256), 0, stream>>>(ws + OFF_LN2, w1w, ws + OFF_H);
  gemm_kernel<1><<<dim3(256), dim3(256), 0, stream>>>(ws + OFF_H, w2w, out);
}

// Round 3
// 354.349 us; speedup vs baseline: 1.1697x; 1.1697x over previous
//
#include <hip/hip_runtime.h>
#include <float.h>

#define NB 32
#define D  2048
#define NC 1023
#define RPB 8   // attn rows per block

typedef float f32x4 __attribute__((ext_vector_type(4)));

// ws layout (float offsets)
#define OFF_LN   0                      // ln_feat [NB*D]
#define OFF_SW   (NB*D)                 // float2 sw[NB][NC]
#define OFF_MM   (OFF_SW + 2*NB*NC)     // smax[NB], smin[NB]
#define OFF_OUT1 (OFF_MM + 2*NB)        // out1 [NB*D]
#define OFF_LN2  (OFF_OUT1 + NB*D)      // ln2  [NB*D]
#define OFF_H    (OFF_LN2 + NB*D)       // h    [NB*D]

__device__ __forceinline__ float wred_sum(float x){
  #pragma unroll
  for (int o = 32; o; o >>= 1) x += __shfl_xor(x, o);
  return x;
}

// ---------------------------------------------------------------------------
// Kernel 1: per-batch prep. LN1, gather, kq/vw fold, s/w vectors, smax/smin.
// ---------------------------------------------------------------------------
__global__ __launch_bounds__(256) void prep_kernel(
    const float* __restrict__ feat, const int* __restrict__ idx,
    const float* __restrict__ ln_w, const float* __restrict__ ln_b,
    const float* __restrict__ q_w,  const float* __restrict__ k_w,
    const float* __restrict__ v_w,  const float* __restrict__ conv_w,
    float* __restrict__ ws)
{
  __shared__ float sh_feat[D];
  __shared__ float sh_shuf[D];
  __shared__ float red_s[4][2];
  __shared__ float red_k[4][8];
  __shared__ float red_mm[4][2];

  const int b = blockIdx.x;
  const int t = threadIdx.x;
  const int wid = t >> 6;

  // ---- load features row into LDS + sum/sumsq
  const float4* fb4 = (const float4*)(feat + b * D);
  float4* sf4 = (float4*)sh_feat;
  float4 fv[2];
  float s1 = 0.f, s2 = 0.f;
  #pragma unroll
  for (int j = 0; j < 2; ++j) {
    float4 v = fb4[t + j * 256];
    fv[j] = v;
    sf4[t + j * 256] = v;
    s1 += (v.x + v.y) + (v.z + v.w);
    s2 += fmaf(v.x, v.x, fmaf(v.y, v.y, fmaf(v.z, v.z, v.w * v.w)));
  }

  // ---- kq[j] = sum_k q_w[k]*k_w[k,j];  vw[j] = sum_v conv_w[v]*v_w[v,j]
  float pk[4] = {0,0,0,0}, pv[4] = {0,0,0,0};
  if (t < 128) {
    float qv = q_w[t], cv = conv_w[t];
    #pragma unroll
    for (int j = 0; j < 4; ++j) {
      pk[j] = qv * k_w[t * 4 + j];
      pv[j] = cv * v_w[t * 4 + j];
    }
  }
  s1 = wred_sum(s1); s2 = wred_sum(s2);
  #pragma unroll
  for (int j = 0; j < 4; ++j) { pk[j] = wred_sum(pk[j]); pv[j] = wred_sum(pv[j]); }
  if ((t & 63) == 0) {
    red_s[wid][0] = s1; red_s[wid][1] = s2;
    #pragma unroll
    for (int j = 0; j < 4; ++j) { red_k[wid][j] = pk[j]; red_k[wid][4 + j] = pv[j]; }
  }
  __syncthreads();

  const float S1 = red_s[0][0] + red_s[1][0] + red_s[2][0] + red_s[3][0];
  const float S2 = red_s[0][1] + red_s[1][1] + red_s[2][1] + red_s[3][1];
  float kq[4], vw[4];
  #pragma unroll
  for (int j = 0; j < 4; ++j) {
    kq[j] = red_k[0][j] + red_k[1][j] + red_k[2][j] + red_k[3][j];
    vw[j] = red_k[0][4+j] + red_k[1][4+j] + red_k[2][4+j] + red_k[3][4+j];
  }
  const float mean = S1 * (1.f / D);
  const float rstd = rsqrtf(S2 * (1.f / D) - mean * mean + 1e-5f);

  // ---- write ln_feat (alpha values)
  float* lnp = ws + OFF_LN + b * D;
  const float4* lw4 = (const float4*)ln_w;
  const float4* lb4 = (const float4*)ln_b;
  #pragma unroll
  for (int j = 0; j < 2; ++j) {
    int i = t + j * 256;
    float4 v = fv[j], w = lw4[i], bb = lb4[i], o;
    o.x = (v.x - mean) * rstd * w.x + bb.x;
    o.y = (v.y - mean) * rstd * w.y + bb.y;
    o.z = (v.z - mean) * rstd * w.z + bb.z;
    o.w = (v.w - mean) * rstd * w.w + bb.w;
    ((float4*)lnp)[i] = o;
  }

  // ---- gather shuffled row
  #pragma unroll
  for (int j = 0; j < 8; ++j) {
    int i = t + j * 256;
    sh_shuf[i] = sh_feat[idx[i]];
  }
  __syncthreads();

  // ---- s[c], w[c] + min/max of s
  float2* swp = (float2*)(ws + OFF_SW) + b * NC;
  float lmax = -FLT_MAX, lmin = FLT_MAX;
  #pragma unroll
  for (int j = 0; j < 4; ++j) {
    int c = t + j * 256;
    if (c < NC) {
      float a0 = sh_shuf[2*c], a1 = sh_shuf[2*c+1], a2 = sh_shuf[2*c+2], a3 = sh_shuf[2*c+3];
      float sv = fmaf(a0, kq[0], fmaf(a1, kq[1], fmaf(a2, kq[2], a3 * kq[3])));
      float wv = fmaf(a0, vw[0], fmaf(a1, vw[1], fmaf(a2, vw[2], a3 * vw[3])));
      float2 p; p.x = sv; p.y = wv;
      swp[c] = p;
      lmax = fmaxf(lmax, sv);
      lmin = fminf(lmin, sv);
    }
  }
  #pragma unroll
  for (int o = 32; o; o >>= 1) {
    lmax = fmaxf(lmax, __shfl_xor(lmax, o));
    lmin = fminf(lmin, __shfl_xor(lmin, o));
  }
  if ((t & 63) == 0) { red_mm[wid][0] = lmax; red_mm[wid][1] = lmin; }
  __syncthreads();
  if (t == 0) {
    ws[OFF_MM + b]      = fmaxf(fmaxf(red_mm[0][0], red_mm[1][0]), fmaxf(red_mm[2][0], red_mm[3][0]));
    ws[OFF_MM + NB + b] = fminf(fminf(red_mm[0][1], red_mm[1][1]), fminf(red_mm[2][1], red_mm[3][1]));
  }
}

// ---------------------------------------------------------------------------
// Kernel 2: 8 consecutive rows per block (same b). Phase 1: each wave computes
// e-values for 2 rows into flat-packed LDS + row sums. Phase 2: contiguous
// aligned float4 nontemporal stores of the whole 32736-byte region.
// ---------------------------------------------------------------------------
__global__ __launch_bounds__(256) void attn_kernel(
    const float* __restrict__ feat, float* __restrict__ ws,
    float* __restrict__ out)
{
  __shared__ float ebuf[RPB * 1024];   // flat packed, row r at r*1023 (8184 used)
  __shared__ float sinv[RPB];

  const int row0 = blockIdx.x * RPB;
  const int b = row0 >> 11;
  const int t = threadIdx.x;
  const int wid = t >> 6, lane = t & 63;

  const float smax = ws[OFF_MM + b], smin = ws[OFF_MM + NB + b];
  const float2* sw = (const float2*)(ws + OFF_SW) + b * NC;

  // each wave handles 2 rows
  #pragma unroll
  for (int rr = 0; rr < 2; ++rr) {
    const int r = wid * 2 + rr;
    const int row = row0 + r;
    const float alpha = ws[OFF_LN + row];
    const float m = (alpha >= 0.f) ? alpha * smax : alpha * smin;
    float* eb = ebuf + r * NC;
    float l = 0.f, acc = 0.f;
    #pragma unroll
    for (int j = 0; j < 16; ++j) {
      int c = lane + j * 64;
      if (c < NC) {
        float2 p = sw[c];
        float e = __expf(fmaf(alpha, p.x, -m));
        eb[c] = e;              // stride-4B writes: conflict-free
        l += e;
        acc = fmaf(e, p.y, acc);
      }
    }
    #pragma unroll
    for (int o = 32; o; o >>= 1) { l += __shfl_xor(l, o); acc += __shfl_xor(acc, o); }
    if (lane == 0) {
      float inv = 1.f / l;
      sinv[r] = inv;
      ws[OFF_OUT1 + row] = fmaf(acc, inv, feat[row]);
    }
  }
  __syncthreads();

  // 8*1023 = 8184 floats = 2046 float4, region start 16B-aligned
  f32x4* base = (f32x4*)(out + NB * D + (size_t)row0 * NC);
  const f32x4* eb4 = (const f32x4*)ebuf;
  #pragma unroll
  for (int j = 0; j < 8; ++j) {
    int i4 = t + j * 256;
    if (i4 < 2046) {
      f32x4 v = eb4[i4];                // stride-16B b128: conflict-free
      int g = i4 * 4;
      int r0 = g / NC, r1 = (g + 1) / NC, r2 = (g + 2) / NC, r3 = (g + 3) / NC;
      v.x *= sinv[r0]; v.y *= sinv[r1]; v.z *= sinv[r2]; v.w *= sinv[r3];
      __builtin_nontemporal_store(v, base + i4);
    }
  }
}

// ---------------------------------------------------------------------------
// Kernel 3: LN2 over out1; init h = w1_b, init out = out1 + w2_b.
// ---------------------------------------------------------------------------
__global__ __launch_bounds__(256) void ln2_init_kernel(
    const float* __restrict__ bnw, const float* __restrict__ bnb,
    const float* __restrict__ w1b, const float* __restrict__ w2b,
    float* __restrict__ ws, float* __restrict__ out)
{
  __shared__ float red_s[4][2];
  const int b = blockIdx.x, t = threadIdx.x;
  const int wid = t >> 6;
  const float4* x4 = (const float4*)(ws + OFF_OUT1 + b * D);
  float4 xv[2];
  float s1 = 0.f, s2 = 0.f;
  #pragma unroll
  for (int j = 0; j < 2; ++j) {
    float4 v = x4[t + j * 256];
    xv[j] = v;
    s1 += (v.x + v.y) + (v.z + v.w);
    s2 += fmaf(v.x, v.x, fmaf(v.y, v.y, fmaf(v.z, v.z, v.w * v.w)));
  }
  s1 = wred_sum(s1); s2 = wred_sum(s2);
  if ((t & 63) == 0) { red_s[wid][0] = s1; red_s[wid][1] = s2; }
  __syncthreads();
  const float S1 = red_s[0][0] + red_s[1][0] + red_s[2][0] + red_s[3][0];
  const float S2 = red_s[0][1] + red_s[1][1] + red_s[2][1] + red_s[3][1];
  const float mean = S1 * (1.f / D);
  const float rstd = rsqrtf(S2 * (1.f / D) - mean * mean + 1e-6f);

  float4* ln2p = (float4*)(ws + OFF_LN2 + b * D);
  float4* hp   = (float4*)(ws + OFF_H   + b * D);
  float4* op   = (float4*)out + b * (D / 4);
  const float4* bw4 = (const float4*)bnw;
  const float4* bb4 = (const float4*)bnb;
  const float4* w1b4 = (const float4*)w1b;
  const float4* w2b4 = (const float4*)w2b;
  #pragma unroll
  for (int j = 0; j < 2; ++j) {
    int i = t + j * 256;
    float4 v = xv[j], w = bw4[i], bb = bb4[i], o;
    o.x = (v.x - mean) * rstd * w.x + bb.x;
    o.y = (v.y - mean) * rstd * w.y + bb.y;
    o.z = (v.z - mean) * rstd * w.z + bb.z;
    o.w = (v.w - mean) * rstd * w.w + bb.w;
    ln2p[i] = o;
    hp[i] = w1b4[i];
    float4 w2 = w2b4[i], oo;
    oo.x = v.x + w2.x; oo.y = v.y + w2.y; oo.z = v.z + w2.z; oo.w = v.w + w2.w;
    op[i] = oo;
  }
}

// ---------------------------------------------------------------------------
// Kernels 4/5: out[m,n] += sum_k X[m,k]*W[n,k]   (M=32, N=K=2048)
// grid = 64 n-chunks x 8 k-splits; block 256. RELU applied to X on load.
// ---------------------------------------------------------------------------
template<int RELU>
__global__ __launch_bounds__(256) void gemm_kernel(
    const float* __restrict__ X, const float* __restrict__ W,
    float* __restrict__ out)
{
  __shared__ float xs[32 * 68];
  __shared__ float wt[32 * 68];
  const int nb = blockIdx.x & 63;
  const int kb = blockIdx.x >> 6;          // 0..7
  const int n0 = nb * 32;
  const int t = threadIdx.x;
  const int row = t >> 3, kl = t & 7;      // compute coords
  const int tr = t >> 4, tc = (t & 15) * 4; // staging coords

  float acc[32];
  #pragma unroll
  for (int m = 0; m < 32; ++m) acc[m] = 0.f;

  for (int ch = 0; ch < 4; ++ch) {
    const int kc = kb * 256 + ch * 64;
    #pragma unroll
    for (int jj = 0; jj < 2; ++jj) {
      int r = tr + jj * 16;
      float4 v = *(const float4*)(X + r * 2048 + kc + tc);
      if (RELU) {
        v.x = fmaxf(v.x, 0.f); v.y = fmaxf(v.y, 0.f);
        v.z = fmaxf(v.z, 0.f); v.w = fmaxf(v.w, 0.f);
      }
      *(float4*)(xs + r * 68 + tc) = v;
      float4 wv = *(const float4*)(W + (n0 + r) * 2048 + kc + tc);
      *(float4*)(wt + r * 68 + tc) = wv;
    }
    __syncthreads();
    const float4 wa = *(float4*)(wt + row * 68 + kl * 8);
    const float4 wb = *(float4*)(wt + row * 68 + kl * 8 + 4);
    #pragma unroll
    for (int m = 0; m < 32; ++m) {
      float4 xa = *(float4*)(xs + m * 68 + kl * 8);
      float4 xb = *(float4*)(xs + m * 68 + kl * 8 + 4);
      acc[m] = fmaf(xa.x, wa.x, fmaf(xa.y, wa.y, fmaf(xa.z, wa.z, fmaf(xa.w, wa.w,
               fmaf(xb.x, wb.x, fmaf(xb.y, wb.y, fmaf(xb.z, wb.z, fmaf(xb.w, wb.w, acc[m]))))))));
    }
    __syncthreads();
  }
  #pragma unroll
  for (int m = 0; m < 32; ++m) {
    acc[m] += __shfl_xor(acc[m], 1);
    acc[m] += __shfl_xor(acc[m], 2);
    acc[m] += __shfl_xor(acc[m], 4);
  }
  #pragma unroll
  for (int i = 0; i < 4; ++i) {
    int m = kl * 4 + i;
    atomicAdd(out + m * 2048 + n0 + row, acc[m]);
  }
}

// ---------------------------------------------------------------------------
extern "C" void kernel_launch(void* const* d_in, const int* in_sizes, int n_in,
                              void* d_out, int out_size, void* d_ws, size_t ws_size,
                              hipStream_t stream)
{
  (void)in_sizes; (void)n_in; (void)out_size; (void)ws_size;
  const float* feat   = (const float*)d_in[0];
  const int*   idx    = (const int*)d_in[1];
  const float* ln_w   = (const float*)d_in[2];
  const float* ln_b   = (const float*)d_in[3];
  const float* q_w    = (const float*)d_in[4];
  const float* k_w    = (const float*)d_in[5];
  const float* v_w    = (const float*)d_in[6];
  const float* conv_w = (const float*)d_in[7];
  const float* bnw    = (const float*)d_in[8];
  const float* bnb    = (const float*)d_in[9];
  const float* w1w    = (const float*)d_in[10];
  const float* w1b    = (const float*)d_in[11];
  const float* w2w    = (const float*)d_in[12];
  const float* w2b    = (const float*)d_in[13];
  float* out = (float*)d_out;
  float* ws  = (float*)d_ws;

  prep_kernel<<<dim3(NB), dim3(256), 0, stream>>>(feat, idx, ln_w, ln_b, q_w, k_w, v_w, conv_w, ws);
  attn_kernel<<<dim3(NB * D / RPB), dim3(256), 0, stream>>>(feat, ws, out);
  ln2_init_kernel<<<dim3(NB), dim3(256), 0, stream>>>(bnw, bnb, w1b, w2b, ws, out);
  gemm_kernel<0><<<dim3(512), dim3(256), 0, stream>>>(ws + OFF_LN2, w1w, ws + OFF_H);
  gemm_kernel<1><<<dim3(512), dim3(256), 0, stream>>>(ws + OFF_H, w2w, out);
}